// Round 3
// baseline (2232.601 us; speedup 1.0000x reference)
//
#include <hip/hip_runtime.h>

#define NB  8
#define NPT 4096
#define NS  1024
#define NK  32
#define DIN 6

// ---------------------------------------------------------------------------
// BN (eval mode) + ReLU applied to a linear accumulator.
// ---------------------------------------------------------------------------
__device__ __forceinline__ float bnrelu(float acc, const float* __restrict__ bb,
                                        const float* __restrict__ gg,
                                        const float* __restrict__ be,
                                        const float* __restrict__ mm,
                                        const float* __restrict__ vv, int oc) {
  float t = (acc + bb[oc]) - mm[oc];
  float val = gg[oc] * t * rsqrtf(vv[oc] + 1e-5f) + be[oc];
  return fmaxf(val, 0.0f);
}

// ---------------------------------------------------------------------------
// Wave64 max via DPP (row_shr 1/2/4/8 + row_bcast15/31), result broadcast via
// readlane(63). ~12 VALU ops instead of a 6-deep ds_bpermute chain.
// Identity = -1.0f (distances are >= 0).
// ---------------------------------------------------------------------------
__device__ __forceinline__ float wave64_max(float x) {
  const int NEG1 = 0xbf800000;  // -1.0f bits
  int v;
  v = __builtin_amdgcn_update_dpp(NEG1, __float_as_int(x), 0x111, 0xf, 0xf, false);
  x = fmaxf(x, __int_as_float(v));  // row_shr:1
  v = __builtin_amdgcn_update_dpp(NEG1, __float_as_int(x), 0x112, 0xf, 0xf, false);
  x = fmaxf(x, __int_as_float(v));  // row_shr:2
  v = __builtin_amdgcn_update_dpp(NEG1, __float_as_int(x), 0x114, 0xf, 0xf, false);
  x = fmaxf(x, __int_as_float(v));  // row_shr:4
  v = __builtin_amdgcn_update_dpp(NEG1, __float_as_int(x), 0x118, 0xf, 0xf, false);
  x = fmaxf(x, __int_as_float(v));  // row_shr:8 -> lane15 of each row has row max
  v = __builtin_amdgcn_update_dpp(NEG1, __float_as_int(x), 0x142, 0xa, 0xf, false);
  x = fmaxf(x, __int_as_float(v));  // row_bcast:15 -> lane31/63 have half maxes
  v = __builtin_amdgcn_update_dpp(NEG1, __float_as_int(x), 0x143, 0xc, 0xf, false);
  x = fmaxf(x, __int_as_float(v));  // row_bcast:31 -> lane63 has wave max
  return __int_as_float(__builtin_amdgcn_readlane(__float_as_int(x), 63));
}

// ---------------------------------------------------------------------------
// Kernel 1: farthest point sampling. One block per batch, 512 threads x 8 pts.
// v3: DPP wave-max on the critical path; LDS-buffered outputs; 1 barrier/step.
// Selection semantics identical to verified v1/v2.
// ---------------------------------------------------------------------------
__global__ __launch_bounds__(512) void fps_kernel(const float* __restrict__ xyz,
                                                  int* __restrict__ fps_idx,
                                                  float* __restrict__ nxyz,
                                                  float* __restrict__ out0) {
  const int b = blockIdx.x;
  const int t = threadIdx.x;
  const int lane = t & 63, wid = t >> 6;
  const float* xb = xyz + (size_t)b * 3 * NPT;

  float px[8], py[8], pz[8], dist[8];
  const int base = t * 8;
#pragma unroll
  for (int j = 0; j < 8; ++j) {
    px[j] = xb[base + j];
    py[j] = xb[NPT + base + j];
    pz[j] = xb[2 * NPT + base + j];
    dist[j] = 1e10f;
  }

  __shared__ float s_rv[2][8][4];  // parity-buffered: per wave val,x,y,z
  __shared__ int s_ri[2][8];
  __shared__ float s_ox[NS], s_oy[NS], s_oz[NS];
  __shared__ int s_fi[NS];

  int far = 0;
  float cx = xb[0], cy = xb[NPT], cz = xb[2 * NPT];

  for (int s = 0; s < NS; ++s) {
    if (t == 0) {
      s_ox[s] = cx; s_oy[s] = cy; s_oz[s] = cz; s_fi[s] = far;
    }

    // min-update distances + per-thread first-max (ascending index order)
    float bv = -1.0f, bx = 0.f, by = 0.f, bz = 0.f;
    int bi = 0;
#pragma unroll
    for (int j = 0; j < 8; ++j) {
      float dx = __fsub_rn(px[j], cx);
      float dy = __fsub_rn(py[j], cy);
      float dz = __fsub_rn(pz[j], cz);
      float d = __fadd_rn(__fadd_rn(__fmul_rn(dx, dx), __fmul_rn(dy, dy)),
                          __fmul_rn(dz, dz));
      float nd = fminf(dist[j], d);
      dist[j] = nd;
      if (nd > bv) { bv = nd; bi = base + j; bx = px[j]; by = py[j]; bz = pz[j]; }
    }

    // wave-level max via DPP; first set lane = smallest index
    float mv = wave64_max(bv);
    unsigned long long mmask = __ballot(bv == mv);
    int src = __ffsll(mmask) - 1;
    int wi = __shfl(bi, src);
    float wx = __shfl(bx, src);
    float wy = __shfl(by, src);
    float wz = __shfl(bz, src);

    const int p = s & 1;
    if (lane == 0) {
      s_rv[p][wid][0] = mv; s_rv[p][wid][1] = wx;
      s_rv[p][wid][2] = wy; s_rv[p][wid][3] = wz;
      s_ri[p][wid] = wi;
    }
    __syncthreads();

    float rv[8], rx[8], ry[8], rz[8];
    int ri[8];
#pragma unroll
    for (int w = 0; w < 8; ++w) {
      float4 q = *(const float4*)&s_rv[p][w][0];
      rv[w] = q.x; rx[w] = q.y; ry[w] = q.z; rz[w] = q.w;
      ri[w] = s_ri[p][w];
    }
    float bestv = rv[0];
    float ncx = rx[0], ncy = ry[0], ncz = rz[0];
    int nfar = ri[0];
#pragma unroll
    for (int w = 1; w < 8; ++w) {
      bool better = rv[w] > bestv;  // strict > keeps first (ascending wave)
      bestv = better ? rv[w] : bestv;
      ncx = better ? rx[w] : ncx;
      ncy = better ? ry[w] : ncy;
      ncz = better ? rz[w] : ncz;
      nfar = better ? ri[w] : nfar;
    }
    far = nfar; cx = ncx; cy = ncy; cz = ncz;
  }

  __syncthreads();
  for (int i = t; i < NS; i += 512) {
    float X = s_ox[i], Y = s_oy[i], Z = s_oz[i];
    out0[((size_t)b * 3 + 0) * NS + i] = X;
    out0[((size_t)b * 3 + 1) * NS + i] = Y;
    out0[((size_t)b * 3 + 2) * NS + i] = Z;
    nxyz[((size_t)b * NS + i) * 3 + 0] = X;
    nxyz[((size_t)b * NS + i) * 3 + 1] = Y;
    nxyz[((size_t)b * NS + i) * 3 + 2] = Z;
    fps_idx[b * NS + i] = s_fi[i];
  }
}

// ---------------------------------------------------------------------------
// Kernel 2: center-point MLP + center half of attention scores. (unchanged)
// ---------------------------------------------------------------------------
__global__ __launch_bounds__(64) void center_kernel(
    const float* __restrict__ points, const float* __restrict__ nxyz,
    const int* __restrict__ fps_idx,
    const float* __restrict__ w0, const float* __restrict__ b0,
    const float* __restrict__ g0, const float* __restrict__ be0,
    const float* __restrict__ m0, const float* __restrict__ v0,
    const float* __restrict__ w1, const float* __restrict__ b1,
    const float* __restrict__ g1, const float* __restrict__ be1,
    const float* __restrict__ m1, const float* __restrict__ v1,
    const float* __restrict__ w2, const float* __restrict__ b2,
    const float* __restrict__ g2, const float* __restrict__ be2,
    const float* __restrict__ m2, const float* __restrict__ v2,
    const float* __restrict__ a, float* __restrict__ ceA) {
  const int bs = blockIdx.x;
  const int b = bs >> 10;
  const int t = threadIdx.x;

  __shared__ float ci[9];
  __shared__ float ch1[64];
  __shared__ float ch2[64];
  __shared__ float ch3[128];

  if (t < 9) {
    ci[t] = (t < 3) ? nxyz[(size_t)bs * 3 + t]
                    : points[((size_t)b * DIN + (t - 3)) * NPT + fps_idx[bs]];
  }
  __syncthreads();
  {
    float acc = 0.f;
#pragma unroll
    for (int c = 0; c < 9; ++c) acc = fmaf(ci[c], w0[t * 9 + c], acc);
    ch1[t] = bnrelu(acc, b0, g0, be0, m0, v0, t);
  }
  __syncthreads();
  {
    float acc = 0.f;
#pragma unroll 8
    for (int c = 0; c < 64; ++c) acc = fmaf(ch1[c], w1[t * 64 + c], acc);
    ch2[t] = bnrelu(acc, b1, g1, be1, m1, v1, t);
  }
  __syncthreads();
  for (int oc = t; oc < 128; oc += 64) {
    float acc = 0.f;
#pragma unroll 8
    for (int c = 0; c < 64; ++c) acc = fmaf(ch2[c], w2[oc * 64 + c], acc);
    ch3[oc] = bnrelu(acc, b2, g2, be2, m2, v2, oc);
  }
  __syncthreads();
  for (int oc = t; oc < 128; oc += 64) {
    float acc = 0.f;
#pragma unroll 8
    for (int c = 0; c < 128; ++c) acc = fmaf(ch3[c], a[(3 + c) * 128 + oc], acc);
    ceA[(size_t)bs * 128 + oc] = acc;
  }
}

// ---------------------------------------------------------------------------
// Kernel 3: per-query fused ball query + neighbor MLP + attention.
// v2: barrier-free per-wave ball query (6 barriers total vs ~28);
// LDS 26.8KB -> 6 blocks/CU; h1/h2 share one buffer via reg-staging;
// layer-1 point features read straight from global (L2-resident).
// ---------------------------------------------------------------------------
__global__ __launch_bounds__(256, 6) void main_kernel(
    const float* __restrict__ xyz, const float* __restrict__ points,
    const float* __restrict__ nxyz, const float* __restrict__ ceA,
    const float* __restrict__ w0, const float* __restrict__ b0,
    const float* __restrict__ g0, const float* __restrict__ be0,
    const float* __restrict__ m0, const float* __restrict__ v0,
    const float* __restrict__ w1, const float* __restrict__ b1,
    const float* __restrict__ g1, const float* __restrict__ be1,
    const float* __restrict__ m1, const float* __restrict__ v1,
    const float* __restrict__ w2, const float* __restrict__ b2,
    const float* __restrict__ g2, const float* __restrict__ be2,
    const float* __restrict__ m2, const float* __restrict__ v2,
    const float* __restrict__ a, float* __restrict__ out1) {
  const int bs = blockIdx.x;
  const int b = bs >> 10;
  const int s = bs & 1023;
  const int t = threadIdx.x;
  const int lane = t & 63;
  const int wid = t >> 6;

  __shared__ int s_widx[4][NK];   // per-wave hit lists (index order)
  __shared__ int s_wc[4];         // per-wave hit counts (capped at NK)
  __shared__ int s_idx[NK];
  __shared__ float s_geo[NK][4];  // rel_xyz per neighbor
  __shared__ float s_h[32 * 68];  // h1 then h2 (reused)
  __shared__ float s_u[32 * 132]; // [k]: h3(128), gx,gy,gz, 0

  const float* xb = xyz + (size_t)b * 3 * NPT;
  const float cx = nxyz[(size_t)bs * 3 + 0];
  const float cy = nxyz[(size_t)bs * 3 + 1];
  const float cz = nxyz[(size_t)bs * 3 + 2];

  // ---- ball query: each wave scans its own contiguous quarter ----
  {
    const float R2 = (float)(0.15 * 0.15);  // python f64 product -> f32
    float s2c = __fadd_rn(__fadd_rn(__fmul_rn(cx, cx), __fmul_rn(cy, cy)),
                          __fmul_rn(cz, cz));
    int wcnt = 0;
    for (int g = 0; g < 16; ++g) {
      int n = wid * 1024 + g * 64 + lane;
      float x = xb[n];
      float y = xb[NPT + n];
      float z = xb[2 * NPT + n];
      float pn2 = __fadd_rn(__fadd_rn(__fmul_rn(x, x), __fmul_rn(y, y)),
                            __fmul_rn(z, z));
      float dot = fmaf(cz, z, fmaf(cy, y, __fmul_rn(cx, x)));
      float sqr = __fsub_rn(__fadd_rn(s2c, pn2), __fmul_rn(2.0f, dot));
      bool hit = !(sqr > R2);
      unsigned long long mm = __ballot(hit);
      int pos = wcnt + __popcll(mm & ((1ull << lane) - 1ull));
      if (hit && pos < NK) s_widx[wid][pos] = n;
      wcnt += __popcll(mm);
      if (wcnt >= NK) break;  // wave-uniform
    }
    if (lane == 0) s_wc[wid] = (wcnt < NK) ? wcnt : NK;
  }
  __syncthreads();  // B1

  // ---- merge per-wave lists in index order + gather rel_xyz ----
  if (t < NK) {
    int c0 = s_wc[0], c1 = s_wc[1], c2 = s_wc[2], c3 = s_wc[3];
    int total = c0 + c1 + c2 + c3;
    int cc[4] = {c0, c1, c2, c3};
    int p = (t < total) ? t : 0;  // pad misses with overall-first hit
    int w = 0;
    while (w < 3 && p >= cc[w]) { p -= cc[w]; ++w; }
    int n = s_widx[w][p];
    s_idx[t] = n;
    s_geo[t][0] = __fsub_rn(xb[n], cx);
    s_geo[t][1] = __fsub_rn(xb[NPT + n], cy);
    s_geo[t][2] = __fsub_rn(xb[2 * NPT + n], cz);
    s_geo[t][3] = 0.f;
  }
  __syncthreads();  // B2

  const int k = t & 31;
  const int ocg = t >> 5;  // 0..7

  // ---- layer 1: 9 -> 64 (point feats straight from global/L2) ----
  {
    float in0[9];
    in0[0] = s_geo[k][0]; in0[1] = s_geo[k][1]; in0[2] = s_geo[k][2];
    int n = s_idx[k];
    const float* pb = points + (size_t)b * DIN * NPT + n;
#pragma unroll
    for (int c = 0; c < 6; ++c) in0[3 + c] = pb[(size_t)c * NPT];
    int oc0 = ocg * 8;
    float acc[8];
#pragma unroll
    for (int j = 0; j < 8; ++j) {
      float a0 = 0.f;
#pragma unroll
      for (int c = 0; c < 9; ++c) a0 = fmaf(in0[c], w0[(oc0 + j) * 9 + c], a0);
      acc[j] = bnrelu(a0, b0, g0, be0, m0, v0, oc0 + j);
    }
    float4* orow = (float4*)&s_h[k * 68 + oc0];
    orow[0] = make_float4(acc[0], acc[1], acc[2], acc[3]);
    orow[1] = make_float4(acc[4], acc[5], acc[6], acc[7]);
  }
  __syncthreads();  // B3

  // ---- layer 2: 64 -> 64 (read h1 -> regs, barrier, overwrite s_h) ----
  {
    int oc0 = ocg * 8;
    float acc[8] = {0.f, 0.f, 0.f, 0.f, 0.f, 0.f, 0.f, 0.f};
    const float4* row = (const float4*)&s_h[k * 68];
#pragma unroll 4
    for (int c4 = 0; c4 < 16; ++c4) {
      float4 hv = row[c4];
#pragma unroll
      for (int j = 0; j < 8; ++j) {
        float4 wv = *(const float4*)&w1[(oc0 + j) * 64 + c4 * 4];
        acc[j] = fmaf(hv.x, wv.x, acc[j]);
        acc[j] = fmaf(hv.y, wv.y, acc[j]);
        acc[j] = fmaf(hv.z, wv.z, acc[j]);
        acc[j] = fmaf(hv.w, wv.w, acc[j]);
      }
    }
#pragma unroll
    for (int j = 0; j < 8; ++j)
      acc[j] = bnrelu(acc[j], b1, g1, be1, m1, v1, oc0 + j);
    __syncthreads();  // B4: all h1 reads done before overwrite
    float4* orow = (float4*)&s_h[k * 68 + oc0];
    orow[0] = make_float4(acc[0], acc[1], acc[2], acc[3]);
    orow[1] = make_float4(acc[4], acc[5], acc[6], acc[7]);
  }
  __syncthreads();  // B5

  // ---- layer 3: 64 -> 128 into s_u[k][0..127]; geo tail ----
  {
    int oc0 = ocg * 16;
    float acc[16];
#pragma unroll
    for (int j = 0; j < 16; ++j) acc[j] = 0.f;
    const float4* row = (const float4*)&s_h[k * 68];
#pragma unroll 2
    for (int c4 = 0; c4 < 16; ++c4) {
      float4 hv = row[c4];
#pragma unroll
      for (int j = 0; j < 16; ++j) {
        float4 wv = *(const float4*)&w2[(oc0 + j) * 64 + c4 * 4];
        acc[j] = fmaf(hv.x, wv.x, acc[j]);
        acc[j] = fmaf(hv.y, wv.y, acc[j]);
        acc[j] = fmaf(hv.z, wv.z, acc[j]);
        acc[j] = fmaf(hv.w, wv.w, acc[j]);
      }
    }
#pragma unroll
    for (int j = 0; j < 16; ++j)
      acc[j] = bnrelu(acc[j], b2, g2, be2, m2, v2, oc0 + j);
    float4* orow = (float4*)&s_u[k * 132 + oc0];
    orow[0] = make_float4(acc[0], acc[1], acc[2], acc[3]);
    orow[1] = make_float4(acc[4], acc[5], acc[6], acc[7]);
    orow[2] = make_float4(acc[8], acc[9], acc[10], acc[11]);
    orow[3] = make_float4(acc[12], acc[13], acc[14], acc[15]);
    if (t < 32) {
      s_u[t * 132 + 128] = s_geo[t][0];
      s_u[t * 132 + 129] = s_geo[t][1];
      s_u[t * 132 + 130] = s_geo[t][2];
      s_u[t * 132 + 131] = 0.f;
    }
  }
  __syncthreads();  // B6

  // ---- attention ----
  {
    int oc0 = ocg * 16;
    float acc[16];
#pragma unroll
    for (int j = 0; j < 16; ++j) acc[j] = 0.f;
    const float4* urow = (const float4*)&s_u[k * 132];
    for (int r4 = 0; r4 < 33; ++r4) {
      float4 uv = urow[r4];
      int r = r4 * 4;
#pragma unroll
      for (int cc = 0; cc < 4; ++cc) {
        int rr = r + cc;
        int arow = (rr < 128) ? (rr + 3) : (rr - 128);  // rr==131 hits a[3]*0
        float uc = (cc == 0) ? uv.x : (cc == 1) ? uv.y : (cc == 2) ? uv.z : uv.w;
        const float4* arp = (const float4*)&a[arow * 128 + oc0];
#pragma unroll
        for (int j4 = 0; j4 < 4; ++j4) {
          float4 av = arp[j4];
          acc[j4 * 4 + 0] = fmaf(uc, av.x, acc[j4 * 4 + 0]);
          acc[j4 * 4 + 1] = fmaf(uc, av.y, acc[j4 * 4 + 1]);
          acc[j4 * 4 + 2] = fmaf(uc, av.z, acc[j4 * 4 + 2]);
          acc[j4 * 4 + 3] = fmaf(uc, av.w, acc[j4 * 4 + 3]);
        }
      }
    }

    float ce[16], h3[16];
#pragma unroll
    for (int j4 = 0; j4 < 4; ++j4) {
      float4 cv = *(const float4*)&ceA[(size_t)bs * 128 + oc0 + j4 * 4];
      ce[j4 * 4 + 0] = cv.x; ce[j4 * 4 + 1] = cv.y;
      ce[j4 * 4 + 2] = cv.z; ce[j4 * 4 + 3] = cv.w;
      float4 hv = *(const float4*)&s_u[k * 132 + oc0 + j4 * 4];
      h3[j4 * 4 + 0] = hv.x; h3[j4 * 4 + 1] = hv.y;
      h3[j4 * 4 + 2] = hv.z; h3[j4 * 4 + 3] = hv.w;
    }

    float* outb = out1 + (size_t)b * 128 * NS + s;
#pragma unroll
    for (int j = 0; j < 16; ++j) {
      float e = ce[j] - acc[j];
      e = (e >= 0.f) ? e : 0.2f * e;  // leaky relu, alpha=0.2
      float mx = e;
#pragma unroll
      for (int off = 16; off > 0; off >>= 1)
        mx = fmaxf(mx, __shfl_xor(mx, off));
      float p = expf(e - mx);
      float num = p * h3[j];
      float den = p;
#pragma unroll
      for (int off = 16; off > 0; off >>= 1) {
        num += __shfl_xor(num, off);
        den += __shfl_xor(den, off);
      }
      if (k == 0) outb[(size_t)(oc0 + j) * NS] = num / den;
    }
  }
}

// ---------------------------------------------------------------------------
extern "C" void kernel_launch(void* const* d_in, const int* in_sizes, int n_in,
                              void* d_out, int out_size, void* d_ws,
                              size_t ws_size, hipStream_t stream) {
  (void)in_sizes; (void)n_in; (void)out_size; (void)ws_size;
  const float* xyz = (const float*)d_in[0];
  const float* points = (const float*)d_in[1];
  const float* w0 = (const float*)d_in[2];
  const float* b0 = (const float*)d_in[3];
  const float* g0 = (const float*)d_in[4];
  const float* be0 = (const float*)d_in[5];
  const float* m0 = (const float*)d_in[6];
  const float* v0 = (const float*)d_in[7];
  const float* w1 = (const float*)d_in[8];
  const float* b1 = (const float*)d_in[9];
  const float* g1 = (const float*)d_in[10];
  const float* be1 = (const float*)d_in[11];
  const float* m1 = (const float*)d_in[12];
  const float* v1 = (const float*)d_in[13];
  const float* w2 = (const float*)d_in[14];
  const float* b2 = (const float*)d_in[15];
  const float* g2 = (const float*)d_in[16];
  const float* be2 = (const float*)d_in[17];
  const float* m2 = (const float*)d_in[18];
  const float* v2 = (const float*)d_in[19];
  const float* a = (const float*)d_in[20];

  float* out0 = (float*)d_out;                  // [B,3,S]
  float* out1 = out0 + (size_t)NB * 3 * NS;     // [B,128,S]

  int* fps = (int*)d_ws;                                   // 8192 ints
  float* nxyz = (float*)((char*)d_ws + 32768);             // 8192*3 floats
  float* ceA = (float*)((char*)d_ws + 32768 + 98304);      // 8192*128 floats

  fps_kernel<<<NB, 512, 0, stream>>>(xyz, fps, nxyz, out0);
  center_kernel<<<NB * NS, 64, 0, stream>>>(points, nxyz, fps,
      w0, b0, g0, be0, m0, v0, w1, b1, g1, be1, m1, v1,
      w2, b2, g2, be2, m2, v2, a, ceA);
  main_kernel<<<NB * NS, 256, 0, stream>>>(xyz, points, nxyz, ceA,
      w0, b0, g0, be0, m0, v0, w1, b1, g1, be1, m1, v1,
      w2, b2, g2, be2, m2, v2, a, out1);
}

// Round 4
// 1633.234 us; speedup vs baseline: 1.3670x; 1.3670x over previous
//
#include <hip/hip_runtime.h>

#define NB  8
#define NPT 4096
#define NS  1024
#define NK  32
#define DIN 6

// ---------------------------------------------------------------------------
// BN (eval mode) + ReLU applied to a linear accumulator.
// ---------------------------------------------------------------------------
__device__ __forceinline__ float bnrelu(float acc, const float* __restrict__ bb,
                                        const float* __restrict__ gg,
                                        const float* __restrict__ be,
                                        const float* __restrict__ mm,
                                        const float* __restrict__ vv, int oc) {
  float t = (acc + bb[oc]) - mm[oc];
  float val = gg[oc] * t * rsqrtf(vv[oc] + 1e-5f) + be[oc];
  return fmaxf(val, 0.0f);
}

// ---------------------------------------------------------------------------
// Wave64 max via DPP (row_shr 1/2/4/8 + row_bcast15/31) + readlane(63).
// Identity = -1.0f (distances are >= 0).
// ---------------------------------------------------------------------------
__device__ __forceinline__ float wave64_max(float x) {
  const int NEG1 = 0xbf800000;  // -1.0f bits
  int v;
  v = __builtin_amdgcn_update_dpp(NEG1, __float_as_int(x), 0x111, 0xf, 0xf, false);
  x = fmaxf(x, __int_as_float(v));  // row_shr:1
  v = __builtin_amdgcn_update_dpp(NEG1, __float_as_int(x), 0x112, 0xf, 0xf, false);
  x = fmaxf(x, __int_as_float(v));  // row_shr:2
  v = __builtin_amdgcn_update_dpp(NEG1, __float_as_int(x), 0x114, 0xf, 0xf, false);
  x = fmaxf(x, __int_as_float(v));  // row_shr:4
  v = __builtin_amdgcn_update_dpp(NEG1, __float_as_int(x), 0x118, 0xf, 0xf, false);
  x = fmaxf(x, __int_as_float(v));  // row_shr:8
  v = __builtin_amdgcn_update_dpp(NEG1, __float_as_int(x), 0x142, 0xa, 0xf, false);
  x = fmaxf(x, __int_as_float(v));  // row_bcast:15
  v = __builtin_amdgcn_update_dpp(NEG1, __float_as_int(x), 0x143, 0xc, 0xf, false);
  x = fmaxf(x, __int_as_float(v));  // row_bcast:31 -> lane63 has wave max
  return __int_as_float(__builtin_amdgcn_readlane(__float_as_int(x), 63));
}

// ---------------------------------------------------------------------------
// Kernel 1: farthest point sampling. One block per batch, 512 threads x 8 pts.
// v4: xyz staged in LDS; winner coords fetched by uniform LDS lookup (no
// coordinate carry through cndmask/shfl); slim (val,idx) reduction slots.
// Selection semantics identical to verified v1-v3: exact __f*_rn distance
// order, per-thread first-max (ascending j), wave ffs(ballot), ascending-wave
// strict-> scan.
// ---------------------------------------------------------------------------
__global__ __launch_bounds__(512) void fps_kernel(const float* __restrict__ xyz,
                                                  int* __restrict__ fps_idx,
                                                  float* __restrict__ nxyz,
                                                  float* __restrict__ out0) {
  const int b = blockIdx.x;
  const int t = threadIdx.x;
  const int lane = t & 63, wid = t >> 6;
  const float* xb = xyz + (size_t)b * 3 * NPT;

  __shared__ float s_x[NPT], s_y[NPT], s_z[NPT];          // 48 KB
  __shared__ __align__(16) float s_red[2][8][2];          // (val, idx bits)
  __shared__ float s_ox[NS], s_oy[NS], s_oz[NS];
  __shared__ int s_fi[NS];

  float px[8], py[8], pz[8], dist[8];
  const int base = t * 8;
#pragma unroll
  for (int j = 0; j < 8; ++j) {
    px[j] = xb[base + j];
    py[j] = xb[NPT + base + j];
    pz[j] = xb[2 * NPT + base + j];
    dist[j] = 1e10f;
  }
  for (int i = t; i < NPT; i += 512) {
    s_x[i] = xb[i];
    s_y[i] = xb[NPT + i];
    s_z[i] = xb[2 * NPT + i];
  }
  __syncthreads();

  int far = 0;
  float cx = xb[0], cy = xb[NPT], cz = xb[2 * NPT];

  for (int s = 0; s < NS; ++s) {
    if (t == 0) {
      s_ox[s] = cx; s_oy[s] = cy; s_oz[s] = cz; s_fi[s] = far;
    }

    // min-update distances + per-thread first-max (ascending index order)
    float bv = -1.0f;
    int bi = 0;
#pragma unroll
    for (int j = 0; j < 8; ++j) {
      float dx = __fsub_rn(px[j], cx);
      float dy = __fsub_rn(py[j], cy);
      float dz = __fsub_rn(pz[j], cz);
      float d = __fadd_rn(__fadd_rn(__fmul_rn(dx, dx), __fmul_rn(dy, dy)),
                          __fmul_rn(dz, dz));
      float nd = fminf(dist[j], d);
      dist[j] = nd;
      bi = (nd > bv) ? (base + j) : bi;
      bv = fmaxf(bv, nd);
    }

    // wave-level max via DPP; first set lane = smallest index
    float mv = wave64_max(bv);
    unsigned long long mmask = __ballot(bv == mv);
    int src = __ffsll(mmask) - 1;
    int wi = __shfl(bi, src);

    const int p = s & 1;
    if (lane == 0) {
      s_red[p][wid][0] = mv;
      s_red[p][wid][1] = __int_as_float(wi);
    }
    __syncthreads();

    // cross-wave scan in registers (ascending wave; strict > keeps first)
    float4 q0 = *(const float4*)&s_red[p][0][0];
    float4 q1 = *(const float4*)&s_red[p][2][0];
    float4 q2 = *(const float4*)&s_red[p][4][0];
    float4 q3 = *(const float4*)&s_red[p][6][0];
    float rv[8] = {q0.x, q0.z, q1.x, q1.z, q2.x, q2.z, q3.x, q3.z};
    int ri[8] = {__float_as_int(q0.y), __float_as_int(q0.w),
                 __float_as_int(q1.y), __float_as_int(q1.w),
                 __float_as_int(q2.y), __float_as_int(q2.w),
                 __float_as_int(q3.y), __float_as_int(q3.w)};
    float bestv = rv[0];
    int nfar = ri[0];
#pragma unroll
    for (int w = 1; w < 8; ++w) {
      bool better = rv[w] > bestv;
      bestv = better ? rv[w] : bestv;
      nfar = better ? ri[w] : nfar;
    }
    far = nfar;
    cx = s_x[far]; cy = s_y[far]; cz = s_z[far];  // uniform LDS broadcast
  }

  __syncthreads();
  for (int i = t; i < NS; i += 512) {
    float X = s_ox[i], Y = s_oy[i], Z = s_oz[i];
    out0[((size_t)b * 3 + 0) * NS + i] = X;
    out0[((size_t)b * 3 + 1) * NS + i] = Y;
    out0[((size_t)b * 3 + 2) * NS + i] = Z;
    nxyz[((size_t)b * NS + i) * 3 + 0] = X;
    nxyz[((size_t)b * NS + i) * 3 + 1] = Y;
    nxyz[((size_t)b * NS + i) * 3 + 2] = Z;
    fps_idx[b * NS + i] = s_fi[i];
  }
}

// ---------------------------------------------------------------------------
// Kernel 2: center-point MLP + center half of attention scores. (unchanged)
// ---------------------------------------------------------------------------
__global__ __launch_bounds__(64) void center_kernel(
    const float* __restrict__ points, const float* __restrict__ nxyz,
    const int* __restrict__ fps_idx,
    const float* __restrict__ w0, const float* __restrict__ b0,
    const float* __restrict__ g0, const float* __restrict__ be0,
    const float* __restrict__ m0, const float* __restrict__ v0,
    const float* __restrict__ w1, const float* __restrict__ b1,
    const float* __restrict__ g1, const float* __restrict__ be1,
    const float* __restrict__ m1, const float* __restrict__ v1,
    const float* __restrict__ w2, const float* __restrict__ b2,
    const float* __restrict__ g2, const float* __restrict__ be2,
    const float* __restrict__ m2, const float* __restrict__ v2,
    const float* __restrict__ a, float* __restrict__ ceA) {
  const int bs = blockIdx.x;
  const int b = bs >> 10;
  const int t = threadIdx.x;

  __shared__ float ci[9];
  __shared__ float ch1[64];
  __shared__ float ch2[64];
  __shared__ float ch3[128];

  if (t < 9) {
    ci[t] = (t < 3) ? nxyz[(size_t)bs * 3 + t]
                    : points[((size_t)b * DIN + (t - 3)) * NPT + fps_idx[bs]];
  }
  __syncthreads();
  {
    float acc = 0.f;
#pragma unroll
    for (int c = 0; c < 9; ++c) acc = fmaf(ci[c], w0[t * 9 + c], acc);
    ch1[t] = bnrelu(acc, b0, g0, be0, m0, v0, t);
  }
  __syncthreads();
  {
    float acc = 0.f;
#pragma unroll 8
    for (int c = 0; c < 64; ++c) acc = fmaf(ch1[c], w1[t * 64 + c], acc);
    ch2[t] = bnrelu(acc, b1, g1, be1, m1, v1, t);
  }
  __syncthreads();
  for (int oc = t; oc < 128; oc += 64) {
    float acc = 0.f;
#pragma unroll 8
    for (int c = 0; c < 64; ++c) acc = fmaf(ch2[c], w2[oc * 64 + c], acc);
    ch3[oc] = bnrelu(acc, b2, g2, be2, m2, v2, oc);
  }
  __syncthreads();
  for (int oc = t; oc < 128; oc += 64) {
    float acc = 0.f;
#pragma unroll 8
    for (int c = 0; c < 128; ++c) acc = fmaf(ch3[c], a[(3 + c) * 128 + oc], acc);
    ceA[(size_t)bs * 128 + oc] = acc;
  }
}

// ---------------------------------------------------------------------------
// Kernel 3: per-query fused ball query + neighbor MLP + attention.
// v3: same as v2 but NO min-waves launch bound (v2's (256,6) spilled:
// VGPR 40, 0.95 GB scratch traffic). LDS 27136 B already allows 6 blocks/CU;
// VGPR ~72 gives 7 waves/SIMD, so occupancy stays LDS-capped at 75%.
// ---------------------------------------------------------------------------
__global__ __launch_bounds__(256) void main_kernel(
    const float* __restrict__ xyz, const float* __restrict__ points,
    const float* __restrict__ nxyz, const float* __restrict__ ceA,
    const float* __restrict__ w0, const float* __restrict__ b0,
    const float* __restrict__ g0, const float* __restrict__ be0,
    const float* __restrict__ m0, const float* __restrict__ v0,
    const float* __restrict__ w1, const float* __restrict__ b1,
    const float* __restrict__ g1, const float* __restrict__ be1,
    const float* __restrict__ m1, const float* __restrict__ v1,
    const float* __restrict__ w2, const float* __restrict__ b2,
    const float* __restrict__ g2, const float* __restrict__ be2,
    const float* __restrict__ m2, const float* __restrict__ v2,
    const float* __restrict__ a, float* __restrict__ out1) {
  const int bs = blockIdx.x;
  const int b = bs >> 10;
  const int s = bs & 1023;
  const int t = threadIdx.x;
  const int lane = t & 63;
  const int wid = t >> 6;

  __shared__ int s_widx[4][NK];   // per-wave hit lists (index order)
  __shared__ int s_wc[4];         // per-wave hit counts (capped at NK)
  __shared__ int s_idx[NK];
  __shared__ float s_geo[NK][4];  // rel_xyz per neighbor
  __shared__ float s_h[32 * 68];  // h1 then h2 (reused)
  __shared__ float s_u[32 * 132]; // [k]: h3(128), gx,gy,gz, 0

  const float* xb = xyz + (size_t)b * 3 * NPT;
  const float cx = nxyz[(size_t)bs * 3 + 0];
  const float cy = nxyz[(size_t)bs * 3 + 1];
  const float cz = nxyz[(size_t)bs * 3 + 2];

  // ---- ball query: each wave scans its own contiguous quarter ----
  {
    const float R2 = (float)(0.15 * 0.15);  // python f64 product -> f32
    float s2c = __fadd_rn(__fadd_rn(__fmul_rn(cx, cx), __fmul_rn(cy, cy)),
                          __fmul_rn(cz, cz));
    int wcnt = 0;
    for (int g = 0; g < 16; ++g) {
      int n = wid * 1024 + g * 64 + lane;
      float x = xb[n];
      float y = xb[NPT + n];
      float z = xb[2 * NPT + n];
      float pn2 = __fadd_rn(__fadd_rn(__fmul_rn(x, x), __fmul_rn(y, y)),
                            __fmul_rn(z, z));
      float dot = fmaf(cz, z, fmaf(cy, y, __fmul_rn(cx, x)));
      float sqr = __fsub_rn(__fadd_rn(s2c, pn2), __fmul_rn(2.0f, dot));
      bool hit = !(sqr > R2);
      unsigned long long mm = __ballot(hit);
      int pos = wcnt + __popcll(mm & ((1ull << lane) - 1ull));
      if (hit && pos < NK) s_widx[wid][pos] = n;
      wcnt += __popcll(mm);
      if (wcnt >= NK) break;  // wave-uniform
    }
    if (lane == 0) s_wc[wid] = (wcnt < NK) ? wcnt : NK;
  }
  __syncthreads();  // B1

  // ---- merge per-wave lists in index order + gather rel_xyz ----
  if (t < NK) {
    int c0 = s_wc[0], c1 = s_wc[1], c2 = s_wc[2], c3 = s_wc[3];
    int total = c0 + c1 + c2 + c3;
    int cc[4] = {c0, c1, c2, c3};
    int p = (t < total) ? t : 0;  // pad misses with overall-first hit
    int w = 0;
    while (w < 3 && p >= cc[w]) { p -= cc[w]; ++w; }
    int n = s_widx[w][p];
    s_idx[t] = n;
    s_geo[t][0] = __fsub_rn(xb[n], cx);
    s_geo[t][1] = __fsub_rn(xb[NPT + n], cy);
    s_geo[t][2] = __fsub_rn(xb[2 * NPT + n], cz);
    s_geo[t][3] = 0.f;
  }
  __syncthreads();  // B2

  const int k = t & 31;
  const int ocg = t >> 5;  // 0..7

  // ---- layer 1: 9 -> 64 (point feats straight from global/L2) ----
  {
    float in0[9];
    in0[0] = s_geo[k][0]; in0[1] = s_geo[k][1]; in0[2] = s_geo[k][2];
    int n = s_idx[k];
    const float* pb = points + (size_t)b * DIN * NPT + n;
#pragma unroll
    for (int c = 0; c < 6; ++c) in0[3 + c] = pb[(size_t)c * NPT];
    int oc0 = ocg * 8;
    float acc[8];
#pragma unroll
    for (int j = 0; j < 8; ++j) {
      float a0 = 0.f;
#pragma unroll
      for (int c = 0; c < 9; ++c) a0 = fmaf(in0[c], w0[(oc0 + j) * 9 + c], a0);
      acc[j] = bnrelu(a0, b0, g0, be0, m0, v0, oc0 + j);
    }
    float4* orow = (float4*)&s_h[k * 68 + oc0];
    orow[0] = make_float4(acc[0], acc[1], acc[2], acc[3]);
    orow[1] = make_float4(acc[4], acc[5], acc[6], acc[7]);
  }
  __syncthreads();  // B3

  // ---- layer 2: 64 -> 64 (read h1 -> regs, barrier, overwrite s_h) ----
  {
    int oc0 = ocg * 8;
    float acc[8] = {0.f, 0.f, 0.f, 0.f, 0.f, 0.f, 0.f, 0.f};
    const float4* row = (const float4*)&s_h[k * 68];
#pragma unroll 4
    for (int c4 = 0; c4 < 16; ++c4) {
      float4 hv = row[c4];
#pragma unroll
      for (int j = 0; j < 8; ++j) {
        float4 wv = *(const float4*)&w1[(oc0 + j) * 64 + c4 * 4];
        acc[j] = fmaf(hv.x, wv.x, acc[j]);
        acc[j] = fmaf(hv.y, wv.y, acc[j]);
        acc[j] = fmaf(hv.z, wv.z, acc[j]);
        acc[j] = fmaf(hv.w, wv.w, acc[j]);
      }
    }
#pragma unroll
    for (int j = 0; j < 8; ++j)
      acc[j] = bnrelu(acc[j], b1, g1, be1, m1, v1, oc0 + j);
    __syncthreads();  // B4: all h1 reads done before overwrite
    float4* orow = (float4*)&s_h[k * 68 + oc0];
    orow[0] = make_float4(acc[0], acc[1], acc[2], acc[3]);
    orow[1] = make_float4(acc[4], acc[5], acc[6], acc[7]);
  }
  __syncthreads();  // B5

  // ---- layer 3: 64 -> 128 into s_u[k][0..127]; geo tail ----
  {
    int oc0 = ocg * 16;
    float acc[16];
#pragma unroll
    for (int j = 0; j < 16; ++j) acc[j] = 0.f;
    const float4* row = (const float4*)&s_h[k * 68];
#pragma unroll 2
    for (int c4 = 0; c4 < 16; ++c4) {
      float4 hv = row[c4];
#pragma unroll
      for (int j = 0; j < 16; ++j) {
        float4 wv = *(const float4*)&w2[(oc0 + j) * 64 + c4 * 4];
        acc[j] = fmaf(hv.x, wv.x, acc[j]);
        acc[j] = fmaf(hv.y, wv.y, acc[j]);
        acc[j] = fmaf(hv.z, wv.z, acc[j]);
        acc[j] = fmaf(hv.w, wv.w, acc[j]);
      }
    }
#pragma unroll
    for (int j = 0; j < 16; ++j)
      acc[j] = bnrelu(acc[j], b2, g2, be2, m2, v2, oc0 + j);
    float4* orow = (float4*)&s_u[k * 132 + oc0];
    orow[0] = make_float4(acc[0], acc[1], acc[2], acc[3]);
    orow[1] = make_float4(acc[4], acc[5], acc[6], acc[7]);
    orow[2] = make_float4(acc[8], acc[9], acc[10], acc[11]);
    orow[3] = make_float4(acc[12], acc[13], acc[14], acc[15]);
    if (t < 32) {
      s_u[t * 132 + 128] = s_geo[t][0];
      s_u[t * 132 + 129] = s_geo[t][1];
      s_u[t * 132 + 130] = s_geo[t][2];
      s_u[t * 132 + 131] = 0.f;
    }
  }
  __syncthreads();  // B6

  // ---- attention ----
  {
    int oc0 = ocg * 16;
    float acc[16];
#pragma unroll
    for (int j = 0; j < 16; ++j) acc[j] = 0.f;
    const float4* urow = (const float4*)&s_u[k * 132];
    for (int r4 = 0; r4 < 33; ++r4) {
      float4 uv = urow[r4];
      int r = r4 * 4;
#pragma unroll
      for (int cc = 0; cc < 4; ++cc) {
        int rr = r + cc;
        int arow = (rr < 128) ? (rr + 3) : (rr - 128);  // rr==131 hits a[3]*0
        float uc = (cc == 0) ? uv.x : (cc == 1) ? uv.y : (cc == 2) ? uv.z : uv.w;
        const float4* arp = (const float4*)&a[arow * 128 + oc0];
#pragma unroll
        for (int j4 = 0; j4 < 4; ++j4) {
          float4 av = arp[j4];
          acc[j4 * 4 + 0] = fmaf(uc, av.x, acc[j4 * 4 + 0]);
          acc[j4 * 4 + 1] = fmaf(uc, av.y, acc[j4 * 4 + 1]);
          acc[j4 * 4 + 2] = fmaf(uc, av.z, acc[j4 * 4 + 2]);
          acc[j4 * 4 + 3] = fmaf(uc, av.w, acc[j4 * 4 + 3]);
        }
      }
    }

    float ce[16], h3[16];
#pragma unroll
    for (int j4 = 0; j4 < 4; ++j4) {
      float4 cv = *(const float4*)&ceA[(size_t)bs * 128 + oc0 + j4 * 4];
      ce[j4 * 4 + 0] = cv.x; ce[j4 * 4 + 1] = cv.y;
      ce[j4 * 4 + 2] = cv.z; ce[j4 * 4 + 3] = cv.w;
      float4 hv = *(const float4*)&s_u[k * 132 + oc0 + j4 * 4];
      h3[j4 * 4 + 0] = hv.x; h3[j4 * 4 + 1] = hv.y;
      h3[j4 * 4 + 2] = hv.z; h3[j4 * 4 + 3] = hv.w;
    }

    float* outb = out1 + (size_t)b * 128 * NS + s;
#pragma unroll
    for (int j = 0; j < 16; ++j) {
      float e = ce[j] - acc[j];
      e = (e >= 0.f) ? e : 0.2f * e;  // leaky relu, alpha=0.2
      float mx = e;
#pragma unroll
      for (int off = 16; off > 0; off >>= 1)
        mx = fmaxf(mx, __shfl_xor(mx, off));
      float p = expf(e - mx);
      float num = p * h3[j];
      float den = p;
#pragma unroll
      for (int off = 16; off > 0; off >>= 1) {
        num += __shfl_xor(num, off);
        den += __shfl_xor(den, off);
      }
      if (k == 0) outb[(size_t)(oc0 + j) * NS] = num / den;
    }
  }
}

// ---------------------------------------------------------------------------
extern "C" void kernel_launch(void* const* d_in, const int* in_sizes, int n_in,
                              void* d_out, int out_size, void* d_ws,
                              size_t ws_size, hipStream_t stream) {
  (void)in_sizes; (void)n_in; (void)out_size; (void)ws_size;
  const float* xyz = (const float*)d_in[0];
  const float* points = (const float*)d_in[1];
  const float* w0 = (const float*)d_in[2];
  const float* b0 = (const float*)d_in[3];
  const float* g0 = (const float*)d_in[4];
  const float* be0 = (const float*)d_in[5];
  const float* m0 = (const float*)d_in[6];
  const float* v0 = (const float*)d_in[7];
  const float* w1 = (const float*)d_in[8];
  const float* b1 = (const float*)d_in[9];
  const float* g1 = (const float*)d_in[10];
  const float* be1 = (const float*)d_in[11];
  const float* m1 = (const float*)d_in[12];
  const float* v1 = (const float*)d_in[13];
  const float* w2 = (const float*)d_in[14];
  const float* b2 = (const float*)d_in[15];
  const float* g2 = (const float*)d_in[16];
  const float* be2 = (const float*)d_in[17];
  const float* m2 = (const float*)d_in[18];
  const float* v2 = (const float*)d_in[19];
  const float* a = (const float*)d_in[20];

  float* out0 = (float*)d_out;                  // [B,3,S]
  float* out1 = out0 + (size_t)NB * 3 * NS;     // [B,128,S]

  int* fps = (int*)d_ws;                                   // 8192 ints
  float* nxyz = (float*)((char*)d_ws + 32768);             // 8192*3 floats
  float* ceA = (float*)((char*)d_ws + 32768 + 98304);      // 8192*128 floats

  fps_kernel<<<NB, 512, 0, stream>>>(xyz, fps, nxyz, out0);
  center_kernel<<<NB * NS, 64, 0, stream>>>(points, nxyz, fps,
      w0, b0, g0, be0, m0, v0, w1, b1, g1, be1, m1, v1,
      w2, b2, g2, be2, m2, v2, a, ceA);
  main_kernel<<<NB * NS, 256, 0, stream>>>(xyz, points, nxyz, ceA,
      w0, b0, g0, be0, m0, v0, w1, b1, g1, be1, m1, v1,
      w2, b2, g2, be2, m2, v2, a, out1);
}

// Round 6
// 1295.939 us; speedup vs baseline: 1.7228x; 1.2603x over previous
//
#include <hip/hip_runtime.h>

#define NB  8
#define NPT 4096
#define NS  1024
#define NK  32
#define DIN 6
#define QPB 32          // queries per mega-block
#define MEGA_THREADS 512

// LDS float counts
#define OFF_A   0            // 131*128 = 16768
#define OFF_W1  16768        // 64*64   = 4096
#define OFF_W2  20864        // 128*64  = 8192
#define OFF_W0  29056        // 64*9    = 576
#define OFF_H   29632        // 32*68   = 2176
#define OFF_U   31808        // 32*132  = 4224
#define OFF_NB  36032        // 32*12   = 384
#define FLT_TOT 36416
#define SMEM_BYTES (FLT_TOT * 4 + (8 * NK + 8 + NK) * 4)   // 146848

// ---------------------------------------------------------------------------
__device__ __forceinline__ float bnrelu(float acc, const float* __restrict__ bb,
                                        const float* __restrict__ gg,
                                        const float* __restrict__ be,
                                        const float* __restrict__ mm,
                                        const float* __restrict__ vv, int oc) {
  float t = (acc + bb[oc]) - mm[oc];
  float val = gg[oc] * t * rsqrtf(vv[oc] + 1e-5f) + be[oc];
  return fmaxf(val, 0.0f);
}

// ---------------------------------------------------------------------------
// Wave64 max via DPP + readlane(63). Identity = -1.0f.
// ---------------------------------------------------------------------------
__device__ __forceinline__ float wave64_max(float x) {
  const int NEG1 = 0xbf800000;
  int v;
  v = __builtin_amdgcn_update_dpp(NEG1, __float_as_int(x), 0x111, 0xf, 0xf, false);
  x = fmaxf(x, __int_as_float(v));
  v = __builtin_amdgcn_update_dpp(NEG1, __float_as_int(x), 0x112, 0xf, 0xf, false);
  x = fmaxf(x, __int_as_float(v));
  v = __builtin_amdgcn_update_dpp(NEG1, __float_as_int(x), 0x114, 0xf, 0xf, false);
  x = fmaxf(x, __int_as_float(v));
  v = __builtin_amdgcn_update_dpp(NEG1, __float_as_int(x), 0x118, 0xf, 0xf, false);
  x = fmaxf(x, __int_as_float(v));
  v = __builtin_amdgcn_update_dpp(NEG1, __float_as_int(x), 0x142, 0xa, 0xf, false);
  x = fmaxf(x, __int_as_float(v));
  v = __builtin_amdgcn_update_dpp(NEG1, __float_as_int(x), 0x143, 0xc, 0xf, false);
  x = fmaxf(x, __int_as_float(v));
  return __int_as_float(__builtin_amdgcn_readlane(__float_as_int(x), 63));
}

// ---------------------------------------------------------------------------
// Kernel 1: FPS (unchanged from verified R4 v4).
// ---------------------------------------------------------------------------
__global__ __launch_bounds__(512) void fps_kernel(const float* __restrict__ xyz,
                                                  int* __restrict__ fps_idx,
                                                  float* __restrict__ nxyz,
                                                  float* __restrict__ out0) {
  const int b = blockIdx.x;
  const int t = threadIdx.x;
  const int lane = t & 63, wid = t >> 6;
  const float* xb = xyz + (size_t)b * 3 * NPT;

  __shared__ float s_x[NPT], s_y[NPT], s_z[NPT];
  __shared__ __align__(16) float s_red[2][8][2];
  __shared__ float s_ox[NS], s_oy[NS], s_oz[NS];
  __shared__ int s_fi[NS];

  float px[8], py[8], pz[8], dist[8];
  const int base = t * 8;
#pragma unroll
  for (int j = 0; j < 8; ++j) {
    px[j] = xb[base + j];
    py[j] = xb[NPT + base + j];
    pz[j] = xb[2 * NPT + base + j];
    dist[j] = 1e10f;
  }
  for (int i = t; i < NPT; i += 512) {
    s_x[i] = xb[i];
    s_y[i] = xb[NPT + i];
    s_z[i] = xb[2 * NPT + i];
  }
  __syncthreads();

  int far = 0;
  float cx = xb[0], cy = xb[NPT], cz = xb[2 * NPT];

  for (int s = 0; s < NS; ++s) {
    if (t == 0) {
      s_ox[s] = cx; s_oy[s] = cy; s_oz[s] = cz; s_fi[s] = far;
    }
    float bv = -1.0f;
    int bi = 0;
#pragma unroll
    for (int j = 0; j < 8; ++j) {
      float dx = __fsub_rn(px[j], cx);
      float dy = __fsub_rn(py[j], cy);
      float dz = __fsub_rn(pz[j], cz);
      float d = __fadd_rn(__fadd_rn(__fmul_rn(dx, dx), __fmul_rn(dy, dy)),
                          __fmul_rn(dz, dz));
      float nd = fminf(dist[j], d);
      dist[j] = nd;
      bi = (nd > bv) ? (base + j) : bi;
      bv = fmaxf(bv, nd);
    }
    float mv = wave64_max(bv);
    unsigned long long mmask = __ballot(bv == mv);
    int src = __ffsll(mmask) - 1;
    int wi = __shfl(bi, src);

    const int p = s & 1;
    if (lane == 0) {
      s_red[p][wid][0] = mv;
      s_red[p][wid][1] = __int_as_float(wi);
    }
    __syncthreads();

    float4 q0 = *(const float4*)&s_red[p][0][0];
    float4 q1 = *(const float4*)&s_red[p][2][0];
    float4 q2 = *(const float4*)&s_red[p][4][0];
    float4 q3 = *(const float4*)&s_red[p][6][0];
    float rv[8] = {q0.x, q0.z, q1.x, q1.z, q2.x, q2.z, q3.x, q3.z};
    int ri[8] = {__float_as_int(q0.y), __float_as_int(q0.w),
                 __float_as_int(q1.y), __float_as_int(q1.w),
                 __float_as_int(q2.y), __float_as_int(q2.w),
                 __float_as_int(q3.y), __float_as_int(q3.w)};
    float bestv = rv[0];
    int nfar = ri[0];
#pragma unroll
    for (int w = 1; w < 8; ++w) {
      bool better = rv[w] > bestv;
      bestv = better ? rv[w] : bestv;
      nfar = better ? ri[w] : nfar;
    }
    far = nfar;
    cx = s_x[far]; cy = s_y[far]; cz = s_z[far];
  }

  __syncthreads();
  for (int i = t; i < NS; i += 512) {
    float X = s_ox[i], Y = s_oy[i], Z = s_oz[i];
    out0[((size_t)b * 3 + 0) * NS + i] = X;
    out0[((size_t)b * 3 + 1) * NS + i] = Y;
    out0[((size_t)b * 3 + 2) * NS + i] = Z;
    nxyz[((size_t)b * NS + i) * 3 + 0] = X;
    nxyz[((size_t)b * NS + i) * 3 + 1] = Y;
    nxyz[((size_t)b * NS + i) * 3 + 2] = Z;
    fps_idx[b * NS + i] = s_fi[i];
  }
}

// ---------------------------------------------------------------------------
// Kernel 2: center-point MLP + center half of attention scores. (unchanged)
// ---------------------------------------------------------------------------
__global__ __launch_bounds__(64) void center_kernel(
    const float* __restrict__ points, const float* __restrict__ nxyz,
    const int* __restrict__ fps_idx,
    const float* __restrict__ w0, const float* __restrict__ b0,
    const float* __restrict__ g0, const float* __restrict__ be0,
    const float* __restrict__ m0, const float* __restrict__ v0,
    const float* __restrict__ w1, const float* __restrict__ b1,
    const float* __restrict__ g1, const float* __restrict__ be1,
    const float* __restrict__ m1, const float* __restrict__ v1,
    const float* __restrict__ w2, const float* __restrict__ b2,
    const float* __restrict__ g2, const float* __restrict__ be2,
    const float* __restrict__ m2, const float* __restrict__ v2,
    const float* __restrict__ a, float* __restrict__ ceA) {
  const int bs = blockIdx.x;
  const int b = bs >> 10;
  const int t = threadIdx.x;

  __shared__ float ci[9];
  __shared__ float ch1[64];
  __shared__ float ch2[64];
  __shared__ float ch3[128];

  if (t < 9) {
    ci[t] = (t < 3) ? nxyz[(size_t)bs * 3 + t]
                    : points[((size_t)b * DIN + (t - 3)) * NPT + fps_idx[bs]];
  }
  __syncthreads();
  {
    float acc = 0.f;
#pragma unroll
    for (int c = 0; c < 9; ++c) acc = fmaf(ci[c], w0[t * 9 + c], acc);
    ch1[t] = bnrelu(acc, b0, g0, be0, m0, v0, t);
  }
  __syncthreads();
  {
    float acc = 0.f;
#pragma unroll 8
    for (int c = 0; c < 64; ++c) acc = fmaf(ch1[c], w1[t * 64 + c], acc);
    ch2[t] = bnrelu(acc, b1, g1, be1, m1, v1, t);
  }
  __syncthreads();
  for (int oc = t; oc < 128; oc += 64) {
    float acc = 0.f;
#pragma unroll 8
    for (int c = 0; c < 64; ++c) acc = fmaf(ch2[c], w2[oc * 64 + c], acc);
    ch3[oc] = bnrelu(acc, b2, g2, be2, m2, v2, oc);
  }
  __syncthreads();
  for (int oc = t; oc < 128; oc += 64) {
    float acc = 0.f;
#pragma unroll 8
    for (int c = 0; c < 128; ++c) acc = fmaf(ch3[c], a[(3 + c) * 128 + oc], acc);
    ceA[(size_t)bs * 128 + oc] = acc;
  }
}

// ---------------------------------------------------------------------------
// Kernel 3 (mega): 256 blocks x 512 threads; 32 queries per block; ALL
// weights (a, w0, w1, w2 = 118 KB) staged in LDS once per block.
// FIX vs R5: w0 staging loop now strided (576 > 512 threads left
// s_w0[512..575] poisoned -> layer-1 oc 57..63 garbage -> absmax 2.22).
// ---------------------------------------------------------------------------
__global__ __launch_bounds__(MEGA_THREADS) void mega_kernel(
    const float* __restrict__ xyz, const float* __restrict__ points,
    const float* __restrict__ nxyz, const float* __restrict__ ceA,
    const float* __restrict__ w0, const float* __restrict__ b0,
    const float* __restrict__ g0, const float* __restrict__ be0,
    const float* __restrict__ m0, const float* __restrict__ v0,
    const float* __restrict__ w1, const float* __restrict__ b1,
    const float* __restrict__ g1, const float* __restrict__ be1,
    const float* __restrict__ m1, const float* __restrict__ v1,
    const float* __restrict__ w2, const float* __restrict__ b2,
    const float* __restrict__ g2, const float* __restrict__ be2,
    const float* __restrict__ m2, const float* __restrict__ v2,
    const float* __restrict__ a, float* __restrict__ out1) {
  extern __shared__ float lds[];
  float* s_a  = lds + OFF_A;
  float* s_w1 = lds + OFF_W1;
  float* s_w2 = lds + OFF_W2;
  float* s_w0 = lds + OFF_W0;
  float* s_h  = lds + OFF_H;
  float* s_u  = lds + OFF_U;
  float* s_nb = lds + OFF_NB;
  int* s_widx = (int*)(lds + FLT_TOT);          // [8][NK]
  int* s_wc   = s_widx + 8 * NK;                // [8]
  int* s_idx  = s_wc + 8;                       // [NK]

  const int t = threadIdx.x;
  const int lane = t & 63;
  const int wvid = t >> 6;          // wave 0..7
  const int k = t & 31;             // neighbor row
  const int g16 = t >> 5;           // oc group 0..15

  // ---- stage weights into LDS (once per block) ----
  {
    const float4* srcA = (const float4*)a;
    float4* dstA = (float4*)s_a;
    for (int i = t; i < 4192; i += MEGA_THREADS) dstA[i] = srcA[i];
    const float4* src1 = (const float4*)w1;
    float4* dst1 = (float4*)s_w1;
    for (int i = t; i < 1024; i += MEGA_THREADS) dst1[i] = src1[i];
    const float4* src2 = (const float4*)w2;
    float4* dst2 = (float4*)s_w2;
    for (int i = t; i < 2048; i += MEGA_THREADS) dst2[i] = src2[i];
    for (int i = t; i < 576; i += MEGA_THREADS) s_w0[i] = w0[i];  // FIXED
  }
  __syncthreads();

  for (int q = 0; q < QPB; ++q) {
    const int bs = blockIdx.x * QPB + q;
    const int b = bs >> 10;
    const int s = bs & 1023;
    const float* xb = xyz + (size_t)b * 3 * NPT;
    const float cx = nxyz[(size_t)bs * 3 + 0];
    const float cy = nxyz[(size_t)bs * 3 + 1];
    const float cz = nxyz[(size_t)bs * 3 + 2];

    // ---- A: ball query, each wave scans its own 512-point range ----
    {
      const float R2 = (float)(0.15 * 0.15);
      float s2c = __fadd_rn(__fadd_rn(__fmul_rn(cx, cx), __fmul_rn(cy, cy)),
                            __fmul_rn(cz, cz));
      int wcnt = 0;
      for (int g = 0; g < 8; ++g) {
        int n = wvid * 512 + g * 64 + lane;
        float x = xb[n];
        float y = xb[NPT + n];
        float z = xb[2 * NPT + n];
        float pn2 = __fadd_rn(__fadd_rn(__fmul_rn(x, x), __fmul_rn(y, y)),
                              __fmul_rn(z, z));
        float dot = fmaf(cz, z, fmaf(cy, y, __fmul_rn(cx, x)));
        float sqr = __fsub_rn(__fadd_rn(s2c, pn2), __fmul_rn(2.0f, dot));
        bool hit = !(sqr > R2);
        unsigned long long mm = __ballot(hit);
        int pos = wcnt + __popcll(mm & ((1ull << lane) - 1ull));
        if (hit && pos < NK) s_widx[wvid * NK + pos] = n;
        wcnt += __popcll(mm);
        if (wcnt >= NK) break;  // wave-uniform
      }
      if (lane == 0) s_wc[wvid] = (wcnt < NK) ? wcnt : NK;
    }
    __syncthreads();

    // ---- B: merge in ascending index order + gather geo/features ----
    if (t < NK) {
      int cc[8];
#pragma unroll
      for (int w = 0; w < 8; ++w) cc[w] = s_wc[w];
      int total = 0;
#pragma unroll
      for (int w = 0; w < 8; ++w) total += cc[w];
      int p = (t < total) ? t : 0;  // pad misses with overall-first hit
      int w = 0;
      while (w < 7 && p >= cc[w]) { p -= cc[w]; ++w; }
      int n = s_widx[w * NK + p];
      s_idx[t] = n;
      s_nb[t * 12 + 0] = __fsub_rn(xb[n], cx);
      s_nb[t * 12 + 1] = __fsub_rn(xb[NPT + n], cy);
      s_nb[t * 12 + 2] = __fsub_rn(xb[2 * NPT + n], cz);
      const float* pb = points + (size_t)b * DIN * NPT + n;
#pragma unroll
      for (int c = 0; c < 6; ++c) s_nb[t * 12 + 3 + c] = pb[(size_t)c * NPT];
      s_nb[t * 12 + 9] = 0.f; s_nb[t * 12 + 10] = 0.f; s_nb[t * 12 + 11] = 0.f;
    }
    __syncthreads();

    // ---- C: layer 1, 9 -> 64 (oc = g16*4 + j) ----
    {
      const float4* nrow = (const float4*)&s_nb[k * 12];
      float4 r0 = nrow[0], r1 = nrow[1], r2 = nrow[2];
      float in0[9] = {r0.x, r0.y, r0.z, r0.w, r1.x, r1.y, r1.z, r1.w, r2.x};
      int oc0 = g16 * 4;
      float acc[4];
#pragma unroll
      for (int j = 0; j < 4; ++j) {
        float a0 = 0.f;
#pragma unroll
        for (int c = 0; c < 9; ++c)
          a0 = fmaf(in0[c], s_w0[(oc0 + j) * 9 + c], a0);
        acc[j] = bnrelu(a0, b0, g0, be0, m0, v0, oc0 + j);
      }
      *(float4*)&s_h[k * 68 + oc0] = make_float4(acc[0], acc[1], acc[2], acc[3]);
    }
    __syncthreads();

    // ---- D: layer 2, 64 -> 64 (oc = g16*4 + j) ----
    {
      int oc0 = g16 * 4;
      float acc[4] = {0.f, 0.f, 0.f, 0.f};
      const float4* row = (const float4*)&s_h[k * 68];
#pragma unroll 4
      for (int c4 = 0; c4 < 16; ++c4) {
        float4 hv = row[c4];
#pragma unroll
        for (int j = 0; j < 4; ++j) {
          float4 wv = *(const float4*)&s_w1[(oc0 + j) * 64 + c4 * 4];
          acc[j] = fmaf(hv.x, wv.x, acc[j]);
          acc[j] = fmaf(hv.y, wv.y, acc[j]);
          acc[j] = fmaf(hv.z, wv.z, acc[j]);
          acc[j] = fmaf(hv.w, wv.w, acc[j]);
        }
      }
#pragma unroll
      for (int j = 0; j < 4; ++j)
        acc[j] = bnrelu(acc[j], b1, g1, be1, m1, v1, oc0 + j);
      __syncthreads();  // all h1 reads complete before overwrite
      *(float4*)&s_h[k * 68 + oc0] = make_float4(acc[0], acc[1], acc[2], acc[3]);
    }
    __syncthreads();

    // ---- E: layer 3, 64 -> 128 (oc = g16*8 + j) ----
    {
      int oc0 = g16 * 8;
      float acc[8] = {0.f, 0.f, 0.f, 0.f, 0.f, 0.f, 0.f, 0.f};
      const float4* row = (const float4*)&s_h[k * 68];
#pragma unroll 2
      for (int c4 = 0; c4 < 16; ++c4) {
        float4 hv = row[c4];
#pragma unroll
        for (int j = 0; j < 8; ++j) {
          float4 wv = *(const float4*)&s_w2[(oc0 + j) * 64 + c4 * 4];
          acc[j] = fmaf(hv.x, wv.x, acc[j]);
          acc[j] = fmaf(hv.y, wv.y, acc[j]);
          acc[j] = fmaf(hv.z, wv.z, acc[j]);
          acc[j] = fmaf(hv.w, wv.w, acc[j]);
        }
      }
#pragma unroll
      for (int j = 0; j < 8; ++j)
        acc[j] = bnrelu(acc[j], b2, g2, be2, m2, v2, oc0 + j);
      float4* orow = (float4*)&s_u[k * 132 + oc0];
      orow[0] = make_float4(acc[0], acc[1], acc[2], acc[3]);
      orow[1] = make_float4(acc[4], acc[5], acc[6], acc[7]);
      if (t < NK) {
        s_u[t * 132 + 128] = s_nb[t * 12 + 0];
        s_u[t * 132 + 129] = s_nb[t * 12 + 1];
        s_u[t * 132 + 130] = s_nb[t * 12 + 2];
        s_u[t * 132 + 131] = 0.f;
      }
    }
    __syncthreads();

    // ---- F: attention (oc = g16*8 + j), softmax over k in half-wave ----
    {
      int oc0 = g16 * 8;
      float acc[8] = {0.f, 0.f, 0.f, 0.f, 0.f, 0.f, 0.f, 0.f};
      const float4* urow = (const float4*)&s_u[k * 132];
      for (int r4 = 0; r4 < 33; ++r4) {
        float4 uv = urow[r4];
        int r = r4 * 4;
#pragma unroll
        for (int cc = 0; cc < 4; ++cc) {
          int rr = r + cc;
          int arow = (rr < 128) ? (rr + 3) : (rr - 128);  // rr==131 -> a[3]*0
          float uc = (cc == 0) ? uv.x : (cc == 1) ? uv.y : (cc == 2) ? uv.z : uv.w;
          const float4* ap = (const float4*)&s_a[arow * 128 + oc0];
          float4 av0 = ap[0], av1 = ap[1];
          acc[0] = fmaf(uc, av0.x, acc[0]);
          acc[1] = fmaf(uc, av0.y, acc[1]);
          acc[2] = fmaf(uc, av0.z, acc[2]);
          acc[3] = fmaf(uc, av0.w, acc[3]);
          acc[4] = fmaf(uc, av1.x, acc[4]);
          acc[5] = fmaf(uc, av1.y, acc[5]);
          acc[6] = fmaf(uc, av1.z, acc[6]);
          acc[7] = fmaf(uc, av1.w, acc[7]);
        }
      }

      float ce[8], h3[8];
      {
        float4 cv0 = *(const float4*)&ceA[(size_t)bs * 128 + oc0];
        float4 cv1 = *(const float4*)&ceA[(size_t)bs * 128 + oc0 + 4];
        ce[0] = cv0.x; ce[1] = cv0.y; ce[2] = cv0.z; ce[3] = cv0.w;
        ce[4] = cv1.x; ce[5] = cv1.y; ce[6] = cv1.z; ce[7] = cv1.w;
        float4 hv0 = *(const float4*)&s_u[k * 132 + oc0];
        float4 hv1 = *(const float4*)&s_u[k * 132 + oc0 + 4];
        h3[0] = hv0.x; h3[1] = hv0.y; h3[2] = hv0.z; h3[3] = hv0.w;
        h3[4] = hv1.x; h3[5] = hv1.y; h3[6] = hv1.z; h3[7] = hv1.w;
      }

      float* outb = out1 + (size_t)b * 128 * NS + s;
#pragma unroll
      for (int j = 0; j < 8; ++j) {
        float e = ce[j] - acc[j];
        e = (e >= 0.f) ? e : 0.2f * e;  // leaky relu alpha=0.2
        float mx = e;
#pragma unroll
        for (int off = 16; off > 0; off >>= 1)
          mx = fmaxf(mx, __shfl_xor(mx, off));
        float p = expf(e - mx);
        float num = p * h3[j];
        float den = p;
#pragma unroll
        for (int off = 16; off > 0; off >>= 1) {
          num += __shfl_xor(num, off);
          den += __shfl_xor(den, off);
        }
        if (k == 0) outb[(size_t)(oc0 + j) * NS] = num / den;
      }
    }
    __syncthreads();  // protect s_u/s_h/s_nb before next query's phases
  }
}

// ---------------------------------------------------------------------------
extern "C" void kernel_launch(void* const* d_in, const int* in_sizes, int n_in,
                              void* d_out, int out_size, void* d_ws,
                              size_t ws_size, hipStream_t stream) {
  (void)in_sizes; (void)n_in; (void)out_size; (void)ws_size;
  const float* xyz = (const float*)d_in[0];
  const float* points = (const float*)d_in[1];
  const float* w0 = (const float*)d_in[2];
  const float* b0 = (const float*)d_in[3];
  const float* g0 = (const float*)d_in[4];
  const float* be0 = (const float*)d_in[5];
  const float* m0 = (const float*)d_in[6];
  const float* v0 = (const float*)d_in[7];
  const float* w1 = (const float*)d_in[8];
  const float* b1 = (const float*)d_in[9];
  const float* g1 = (const float*)d_in[10];
  const float* be1 = (const float*)d_in[11];
  const float* m1 = (const float*)d_in[12];
  const float* v1 = (const float*)d_in[13];
  const float* w2 = (const float*)d_in[14];
  const float* b2 = (const float*)d_in[15];
  const float* g2 = (const float*)d_in[16];
  const float* be2 = (const float*)d_in[17];
  const float* m2 = (const float*)d_in[18];
  const float* v2 = (const float*)d_in[19];
  const float* a = (const float*)d_in[20];

  float* out0 = (float*)d_out;                  // [B,3,S]
  float* out1 = out0 + (size_t)NB * 3 * NS;     // [B,128,S]

  int* fps = (int*)d_ws;                                   // 8192 ints
  float* nxyz = (float*)((char*)d_ws + 32768);             // 8192*3 floats
  float* ceA = (float*)((char*)d_ws + 32768 + 98304);      // 8192*128 floats

  hipFuncSetAttribute(reinterpret_cast<const void*>(mega_kernel),
                      hipFuncAttributeMaxDynamicSharedMemorySize, SMEM_BYTES);

  fps_kernel<<<NB, 512, 0, stream>>>(xyz, fps, nxyz, out0);
  center_kernel<<<NB * NS, 64, 0, stream>>>(points, nxyz, fps,
      w0, b0, g0, be0, m0, v0, w1, b1, g1, be1, m1, v1,
      w2, b2, g2, be2, m2, v2, a, ceA);
  mega_kernel<<<NB * NS / QPB, MEGA_THREADS, SMEM_BYTES, stream>>>(
      xyz, points, nxyz, ceA,
      w0, b0, g0, be0, m0, v0, w1, b1, g1, be1, m1, v1,
      w2, b2, g2, be2, m2, v2, a, out1);
}

// Round 7
// 1265.246 us; speedup vs baseline: 1.7646x; 1.0243x over previous
//
#include <hip/hip_runtime.h>

#define NB  8
#define NPT 4096
#define NS  1024
#define NK  32
#define DIN 6
#define QPB 32          // queries per mega-block
#define MEGA_THREADS 512

// mega LDS float offsets
#define OFF_A   0            // 131*128 = 16768
#define OFF_W1  16768        // 64*64   = 4096
#define OFF_W2  20864        // 128*64  = 8192
#define OFF_W0  29056        // 64*9    = 576
#define OFF_H1  29632        // 32*68   = 2176
#define OFF_H2  31808        // 32*68   = 2176
#define OFF_U   33984        // 32*132  = 4224
#define FLT_TOT 38208
#define SMEM_BYTES (FLT_TOT * 4)   // 152832 B <= 160 KiB

// ---------------------------------------------------------------------------
__device__ __forceinline__ float bnrelu(float acc, const float* __restrict__ bb,
                                        const float* __restrict__ gg,
                                        const float* __restrict__ be,
                                        const float* __restrict__ mm,
                                        const float* __restrict__ vv, int oc) {
  float t = (acc + bb[oc]) - mm[oc];
  float val = gg[oc] * t * rsqrtf(vv[oc] + 1e-5f) + be[oc];
  return fmaxf(val, 0.0f);
}

// ---------------------------------------------------------------------------
// Wave64 max via DPP + readlane(63). Identity = -1.0f.
// ---------------------------------------------------------------------------
__device__ __forceinline__ float wave64_max(float x) {
  const int NEG1 = 0xbf800000;
  int v;
  v = __builtin_amdgcn_update_dpp(NEG1, __float_as_int(x), 0x111, 0xf, 0xf, false);
  x = fmaxf(x, __int_as_float(v));
  v = __builtin_amdgcn_update_dpp(NEG1, __float_as_int(x), 0x112, 0xf, 0xf, false);
  x = fmaxf(x, __int_as_float(v));
  v = __builtin_amdgcn_update_dpp(NEG1, __float_as_int(x), 0x114, 0xf, 0xf, false);
  x = fmaxf(x, __int_as_float(v));
  v = __builtin_amdgcn_update_dpp(NEG1, __float_as_int(x), 0x118, 0xf, 0xf, false);
  x = fmaxf(x, __int_as_float(v));
  v = __builtin_amdgcn_update_dpp(NEG1, __float_as_int(x), 0x142, 0xa, 0xf, false);
  x = fmaxf(x, __int_as_float(v));
  v = __builtin_amdgcn_update_dpp(NEG1, __float_as_int(x), 0x143, 0xc, 0xf, false);
  x = fmaxf(x, __int_as_float(v));
  return __int_as_float(__builtin_amdgcn_readlane(__float_as_int(x), 63));
}

// ---------------------------------------------------------------------------
// Kernel 1: FPS. v5 = verified v4 + 3-level tournament scan (right wins only
// if strictly greater -> preserves first-max = ascending-wave semantics).
// ---------------------------------------------------------------------------
__global__ __launch_bounds__(512) void fps_kernel(const float* __restrict__ xyz,
                                                  int* __restrict__ fps_idx,
                                                  float* __restrict__ nxyz,
                                                  float* __restrict__ out0) {
  const int b = blockIdx.x;
  const int t = threadIdx.x;
  const int lane = t & 63, wid = t >> 6;
  const float* xb = xyz + (size_t)b * 3 * NPT;

  __shared__ float s_x[NPT], s_y[NPT], s_z[NPT];
  __shared__ __align__(16) float s_red[2][8][2];
  __shared__ float s_ox[NS], s_oy[NS], s_oz[NS];
  __shared__ int s_fi[NS];

  float px[8], py[8], pz[8], dist[8];
  const int base = t * 8;
#pragma unroll
  for (int j = 0; j < 8; ++j) {
    px[j] = xb[base + j];
    py[j] = xb[NPT + base + j];
    pz[j] = xb[2 * NPT + base + j];
    dist[j] = 1e10f;
  }
  for (int i = t; i < NPT; i += 512) {
    s_x[i] = xb[i];
    s_y[i] = xb[NPT + i];
    s_z[i] = xb[2 * NPT + i];
  }
  __syncthreads();

  int far = 0;
  float cx = xb[0], cy = xb[NPT], cz = xb[2 * NPT];

  for (int s = 0; s < NS; ++s) {
    if (t == 0) {
      s_ox[s] = cx; s_oy[s] = cy; s_oz[s] = cz; s_fi[s] = far;
    }
    float bv = -1.0f;
    int bi = 0;
#pragma unroll
    for (int j = 0; j < 8; ++j) {
      float dx = __fsub_rn(px[j], cx);
      float dy = __fsub_rn(py[j], cy);
      float dz = __fsub_rn(pz[j], cz);
      float d = __fadd_rn(__fadd_rn(__fmul_rn(dx, dx), __fmul_rn(dy, dy)),
                          __fmul_rn(dz, dz));
      float nd = fminf(dist[j], d);
      dist[j] = nd;
      bi = (nd > bv) ? (base + j) : bi;
      bv = fmaxf(bv, nd);
    }
    float mv = wave64_max(bv);
    unsigned long long mmask = __ballot(bv == mv);
    int src = __ffsll(mmask) - 1;
    int wi = __shfl(bi, src);

    const int p = s & 1;
    if (lane == 0) {
      s_red[p][wid][0] = mv;
      s_red[p][wid][1] = __int_as_float(wi);
    }
    __syncthreads();

    float4 q0 = *(const float4*)&s_red[p][0][0];
    float4 q1 = *(const float4*)&s_red[p][2][0];
    float4 q2 = *(const float4*)&s_red[p][4][0];
    float4 q3 = *(const float4*)&s_red[p][6][0];
    // tournament: right side wins only on strict >  => first max overall
    float va, vb, vc, vd; int ia, ib, ic, id;
    { bool g = q0.z > q0.x; va = g ? q0.z : q0.x;
      ia = g ? __float_as_int(q0.w) : __float_as_int(q0.y); }
    { bool g = q1.z > q1.x; vb = g ? q1.z : q1.x;
      ib = g ? __float_as_int(q1.w) : __float_as_int(q1.y); }
    { bool g = q2.z > q2.x; vc = g ? q2.z : q2.x;
      ic = g ? __float_as_int(q2.w) : __float_as_int(q2.y); }
    { bool g = q3.z > q3.x; vd = g ? q3.z : q3.x;
      id = g ? __float_as_int(q3.w) : __float_as_int(q3.y); }
    { bool g = vb > va; va = g ? vb : va; ia = g ? ib : ia; }
    { bool g = vd > vc; vc = g ? vd : vc; ic = g ? id : ic; }
    { bool g = vc > va; va = g ? vc : va; ia = g ? ic : ia; }
    far = ia;
    cx = s_x[far]; cy = s_y[far]; cz = s_z[far];
  }

  __syncthreads();
  for (int i = t; i < NS; i += 512) {
    float X = s_ox[i], Y = s_oy[i], Z = s_oz[i];
    out0[((size_t)b * 3 + 0) * NS + i] = X;
    out0[((size_t)b * 3 + 1) * NS + i] = Y;
    out0[((size_t)b * 3 + 2) * NS + i] = Z;
    nxyz[((size_t)b * NS + i) * 3 + 0] = X;
    nxyz[((size_t)b * NS + i) * 3 + 1] = Y;
    nxyz[((size_t)b * NS + i) * 3 + 2] = Z;
    fps_idx[b * NS + i] = s_fi[i];
  }
}

// ---------------------------------------------------------------------------
// Kernel 2: center-point MLP + center half of attention scores. (unchanged)
// ---------------------------------------------------------------------------
__global__ __launch_bounds__(64) void center_kernel(
    const float* __restrict__ points, const float* __restrict__ nxyz,
    const int* __restrict__ fps_idx,
    const float* __restrict__ w0, const float* __restrict__ b0,
    const float* __restrict__ g0, const float* __restrict__ be0,
    const float* __restrict__ m0, const float* __restrict__ v0,
    const float* __restrict__ w1, const float* __restrict__ b1,
    const float* __restrict__ g1, const float* __restrict__ be1,
    const float* __restrict__ m1, const float* __restrict__ v1,
    const float* __restrict__ w2, const float* __restrict__ b2,
    const float* __restrict__ g2, const float* __restrict__ be2,
    const float* __restrict__ m2, const float* __restrict__ v2,
    const float* __restrict__ a, float* __restrict__ ceA) {
  const int bs = blockIdx.x;
  const int b = bs >> 10;
  const int t = threadIdx.x;

  __shared__ float ci[9];
  __shared__ float ch1[64];
  __shared__ float ch2[64];
  __shared__ float ch3[128];

  if (t < 9) {
    ci[t] = (t < 3) ? nxyz[(size_t)bs * 3 + t]
                    : points[((size_t)b * DIN + (t - 3)) * NPT + fps_idx[bs]];
  }
  __syncthreads();
  {
    float acc = 0.f;
#pragma unroll
    for (int c = 0; c < 9; ++c) acc = fmaf(ci[c], w0[t * 9 + c], acc);
    ch1[t] = bnrelu(acc, b0, g0, be0, m0, v0, t);
  }
  __syncthreads();
  {
    float acc = 0.f;
#pragma unroll 8
    for (int c = 0; c < 64; ++c) acc = fmaf(ch1[c], w1[t * 64 + c], acc);
    ch2[t] = bnrelu(acc, b1, g1, be1, m1, v1, t);
  }
  __syncthreads();
  for (int oc = t; oc < 128; oc += 64) {
    float acc = 0.f;
#pragma unroll 8
    for (int c = 0; c < 64; ++c) acc = fmaf(ch2[c], w2[oc * 64 + c], acc);
    ch3[oc] = bnrelu(acc, b2, g2, be2, m2, v2, oc);
  }
  __syncthreads();
  for (int oc = t; oc < 128; oc += 64) {
    float acc = 0.f;
#pragma unroll 8
    for (int c = 0; c < 128; ++c) acc = fmaf(ch3[c], a[(3 + c) * 128 + oc], acc);
    ceA[(size_t)bs * 128 + oc] = acc;
  }
}

// ---------------------------------------------------------------------------
// Kernel 3 (new): standalone ball query + gather. 8192 blocks x 256 threads,
// tiny LDS -> high occupancy; semantics verbatim from verified R4 phase A/B
// (4 waves x contiguous 1024-range, 16 chunks, wave-uniform break, first-32
// merge in ascending index order, pad misses with overall-first hit).
// Output: gq[bs*32+k] = (gx, gy, gz, idx_bits).
// ---------------------------------------------------------------------------
__global__ __launch_bounds__(256) void ballq_kernel(
    const float* __restrict__ xyz, const float* __restrict__ nxyz,
    float4* __restrict__ gq) {
  const int bs = blockIdx.x;
  const int b = bs >> 10;
  const int t = threadIdx.x;
  const int lane = t & 63;
  const int wid = t >> 6;

  __shared__ int s_widx[4][NK];
  __shared__ int s_wc[4];

  const float* xb = xyz + (size_t)b * 3 * NPT;
  const float cx = nxyz[(size_t)bs * 3 + 0];
  const float cy = nxyz[(size_t)bs * 3 + 1];
  const float cz = nxyz[(size_t)bs * 3 + 2];

  {
    const float R2 = (float)(0.15 * 0.15);
    float s2c = __fadd_rn(__fadd_rn(__fmul_rn(cx, cx), __fmul_rn(cy, cy)),
                          __fmul_rn(cz, cz));
    int wcnt = 0;
    for (int g = 0; g < 16; ++g) {
      int n = wid * 1024 + g * 64 + lane;
      float x = xb[n];
      float y = xb[NPT + n];
      float z = xb[2 * NPT + n];
      float pn2 = __fadd_rn(__fadd_rn(__fmul_rn(x, x), __fmul_rn(y, y)),
                            __fmul_rn(z, z));
      float dot = fmaf(cz, z, fmaf(cy, y, __fmul_rn(cx, x)));
      float sqr = __fsub_rn(__fadd_rn(s2c, pn2), __fmul_rn(2.0f, dot));
      bool hit = !(sqr > R2);
      unsigned long long mm = __ballot(hit);
      int pos = wcnt + __popcll(mm & ((1ull << lane) - 1ull));
      if (hit && pos < NK) s_widx[wid][pos] = n;
      wcnt += __popcll(mm);
      if (wcnt >= NK) break;  // wave-uniform
    }
    if (lane == 0) s_wc[wid] = (wcnt < NK) ? wcnt : NK;
  }
  __syncthreads();

  if (t < NK) {
    int c0 = s_wc[0], c1 = s_wc[1], c2 = s_wc[2], c3 = s_wc[3];
    int total = c0 + c1 + c2 + c3;
    int cc[4] = {c0, c1, c2, c3};
    int p = (t < total) ? t : 0;  // pad misses with overall-first hit
    int w = 0;
    while (w < 3 && p >= cc[w]) { p -= cc[w]; ++w; }
    int n = s_widx[w][p];
    float gx = __fsub_rn(xb[n], cx);
    float gy = __fsub_rn(xb[NPT + n], cy);
    float gz = __fsub_rn(xb[2 * NPT + n], cz);
    gq[(size_t)bs * NK + t] = make_float4(gx, gy, gz, __int_as_float(n));
  }
}

// ---------------------------------------------------------------------------
// Kernel 4 (mega v2): pure MLP+attention; ball query hoisted out. 3 barriers
// per query (was 7): C writes h1 |B1| D h1->h2 |B2| E h2->u |B3| F reads u.
// F needs no trailing barrier: it reads only s_u/s_a; the next query's s_u
// writes (phase E) sit behind B1'+B2', and next-C touches only s_h1 whose
// readers (this D) finished before B2. Weights stay LDS-resident.
// ---------------------------------------------------------------------------
__global__ __launch_bounds__(MEGA_THREADS) void mega_kernel(
    const float* __restrict__ points, const float* __restrict__ ceA,
    const float4* __restrict__ gq,
    const float* __restrict__ w0, const float* __restrict__ b0,
    const float* __restrict__ g0, const float* __restrict__ be0,
    const float* __restrict__ m0, const float* __restrict__ v0,
    const float* __restrict__ w1, const float* __restrict__ b1,
    const float* __restrict__ g1, const float* __restrict__ be1,
    const float* __restrict__ m1, const float* __restrict__ v1,
    const float* __restrict__ w2, const float* __restrict__ b2,
    const float* __restrict__ g2, const float* __restrict__ be2,
    const float* __restrict__ m2, const float* __restrict__ v2,
    const float* __restrict__ a, float* __restrict__ out1) {
  extern __shared__ float lds[];
  float* s_a  = lds + OFF_A;
  float* s_w1 = lds + OFF_W1;
  float* s_w2 = lds + OFF_W2;
  float* s_w0 = lds + OFF_W0;
  float* s_h1 = lds + OFF_H1;
  float* s_h2 = lds + OFF_H2;
  float* s_u  = lds + OFF_U;

  const int t = threadIdx.x;
  const int k = t & 31;             // neighbor row
  const int g16 = t >> 5;           // oc group 0..15

  // ---- stage weights into LDS (once per block) ----
  {
    const float4* srcA = (const float4*)a;
    float4* dstA = (float4*)s_a;
    for (int i = t; i < 4192; i += MEGA_THREADS) dstA[i] = srcA[i];
    const float4* src1 = (const float4*)w1;
    float4* dst1 = (float4*)s_w1;
    for (int i = t; i < 1024; i += MEGA_THREADS) dst1[i] = src1[i];
    const float4* src2 = (const float4*)w2;
    float4* dst2 = (float4*)s_w2;
    for (int i = t; i < 2048; i += MEGA_THREADS) dst2[i] = src2[i];
    for (int i = t; i < 576; i += MEGA_THREADS) s_w0[i] = w0[i];
  }
  __syncthreads();

  for (int q = 0; q < QPB; ++q) {
    const int bs = blockIdx.x * QPB + q;
    const int b = bs >> 10;
    const int s = bs & 1023;

    float4 gv = gq[(size_t)bs * NK + k];
    const int n = __float_as_int(gv.w);

    // ---- C: layer 1, 9 -> 64 (oc = g16*4 + j) ----
    {
      float in0[9];
      in0[0] = gv.x; in0[1] = gv.y; in0[2] = gv.z;
      const float* pb = points + (size_t)b * DIN * NPT + n;
#pragma unroll
      for (int c = 0; c < 6; ++c) in0[3 + c] = pb[(size_t)c * NPT];
      int oc0 = g16 * 4;
      float acc[4];
#pragma unroll
      for (int j = 0; j < 4; ++j) {
        float a0 = 0.f;
#pragma unroll
        for (int c = 0; c < 9; ++c)
          a0 = fmaf(in0[c], s_w0[(oc0 + j) * 9 + c], a0);
        acc[j] = bnrelu(a0, b0, g0, be0, m0, v0, oc0 + j);
      }
      *(float4*)&s_h1[k * 68 + oc0] = make_float4(acc[0], acc[1], acc[2], acc[3]);
    }
    __syncthreads();  // B1

    // ---- D: layer 2, 64 -> 64, h1 -> h2 ----
    {
      int oc0 = g16 * 4;
      float acc[4] = {0.f, 0.f, 0.f, 0.f};
      const float4* row = (const float4*)&s_h1[k * 68];
#pragma unroll 4
      for (int c4 = 0; c4 < 16; ++c4) {
        float4 hv = row[c4];
#pragma unroll
        for (int j = 0; j < 4; ++j) {
          float4 wv = *(const float4*)&s_w1[(oc0 + j) * 64 + c4 * 4];
          acc[j] = fmaf(hv.x, wv.x, acc[j]);
          acc[j] = fmaf(hv.y, wv.y, acc[j]);
          acc[j] = fmaf(hv.z, wv.z, acc[j]);
          acc[j] = fmaf(hv.w, wv.w, acc[j]);
        }
      }
#pragma unroll
      for (int j = 0; j < 4; ++j)
        acc[j] = bnrelu(acc[j], b1, g1, be1, m1, v1, oc0 + j);
      *(float4*)&s_h2[k * 68 + oc0] = make_float4(acc[0], acc[1], acc[2], acc[3]);
    }
    __syncthreads();  // B2

    // ---- E: layer 3, 64 -> 128, h2 -> u; geo tail from registers ----
    {
      int oc0 = g16 * 8;
      float acc[8] = {0.f, 0.f, 0.f, 0.f, 0.f, 0.f, 0.f, 0.f};
      const float4* row = (const float4*)&s_h2[k * 68];
#pragma unroll 2
      for (int c4 = 0; c4 < 16; ++c4) {
        float4 hv = row[c4];
#pragma unroll
        for (int j = 0; j < 8; ++j) {
          float4 wv = *(const float4*)&s_w2[(oc0 + j) * 64 + c4 * 4];
          acc[j] = fmaf(hv.x, wv.x, acc[j]);
          acc[j] = fmaf(hv.y, wv.y, acc[j]);
          acc[j] = fmaf(hv.z, wv.z, acc[j]);
          acc[j] = fmaf(hv.w, wv.w, acc[j]);
        }
      }
#pragma unroll
      for (int j = 0; j < 8; ++j)
        acc[j] = bnrelu(acc[j], b2, g2, be2, m2, v2, oc0 + j);
      float4* orow = (float4*)&s_u[k * 132 + oc0];
      orow[0] = make_float4(acc[0], acc[1], acc[2], acc[3]);
      orow[1] = make_float4(acc[4], acc[5], acc[6], acc[7]);
      if (t < NK) {
        s_u[t * 132 + 128] = gv.x;
        s_u[t * 132 + 129] = gv.y;
        s_u[t * 132 + 130] = gv.z;
        s_u[t * 132 + 131] = 0.f;
      }
    }
    __syncthreads();  // B3

    // ---- F: attention (oc = g16*8 + j), softmax over k in half-wave ----
    {
      int oc0 = g16 * 8;
      float acc[8] = {0.f, 0.f, 0.f, 0.f, 0.f, 0.f, 0.f, 0.f};
      const float4* urow = (const float4*)&s_u[k * 132];
      for (int r4 = 0; r4 < 33; ++r4) {
        float4 uv = urow[r4];
        int r = r4 * 4;
#pragma unroll
        for (int cc = 0; cc < 4; ++cc) {
          int rr = r + cc;
          int arow = (rr < 128) ? (rr + 3) : (rr - 128);  // rr==131 -> a[3]*0
          float uc = (cc == 0) ? uv.x : (cc == 1) ? uv.y : (cc == 2) ? uv.z : uv.w;
          const float4* ap = (const float4*)&s_a[arow * 128 + oc0];
          float4 av0 = ap[0], av1 = ap[1];
          acc[0] = fmaf(uc, av0.x, acc[0]);
          acc[1] = fmaf(uc, av0.y, acc[1]);
          acc[2] = fmaf(uc, av0.z, acc[2]);
          acc[3] = fmaf(uc, av0.w, acc[3]);
          acc[4] = fmaf(uc, av1.x, acc[4]);
          acc[5] = fmaf(uc, av1.y, acc[5]);
          acc[6] = fmaf(uc, av1.z, acc[6]);
          acc[7] = fmaf(uc, av1.w, acc[7]);
        }
      }

      float ce[8], h3[8];
      {
        float4 cv0 = *(const float4*)&ceA[(size_t)bs * 128 + oc0];
        float4 cv1 = *(const float4*)&ceA[(size_t)bs * 128 + oc0 + 4];
        ce[0] = cv0.x; ce[1] = cv0.y; ce[2] = cv0.z; ce[3] = cv0.w;
        ce[4] = cv1.x; ce[5] = cv1.y; ce[6] = cv1.z; ce[7] = cv1.w;
        float4 hv0 = *(const float4*)&s_u[k * 132 + oc0];
        float4 hv1 = *(const float4*)&s_u[k * 132 + oc0 + 4];
        h3[0] = hv0.x; h3[1] = hv0.y; h3[2] = hv0.z; h3[3] = hv0.w;
        h3[4] = hv1.x; h3[5] = hv1.y; h3[6] = hv1.z; h3[7] = hv1.w;
      }

      float* outb = out1 + (size_t)b * 128 * NS + s;
#pragma unroll
      for (int j = 0; j < 8; ++j) {
        float e = ce[j] - acc[j];
        e = (e >= 0.f) ? e : 0.2f * e;  // leaky relu alpha=0.2
        float mx = e;
#pragma unroll
        for (int off = 16; off > 0; off >>= 1)
          mx = fmaxf(mx, __shfl_xor(mx, off));
        float p = expf(e - mx);
        float num = p * h3[j];
        float den = p;
#pragma unroll
        for (int off = 16; off > 0; off >>= 1) {
          num += __shfl_xor(num, off);
          den += __shfl_xor(den, off);
        }
        if (k == 0) outb[(size_t)(oc0 + j) * NS] = num / den;
      }
    }
    // no trailing barrier needed (see header comment)
  }
}

// ---------------------------------------------------------------------------
extern "C" void kernel_launch(void* const* d_in, const int* in_sizes, int n_in,
                              void* d_out, int out_size, void* d_ws,
                              size_t ws_size, hipStream_t stream) {
  (void)in_sizes; (void)n_in; (void)out_size; (void)ws_size;
  const float* xyz = (const float*)d_in[0];
  const float* points = (const float*)d_in[1];
  const float* w0 = (const float*)d_in[2];
  const float* b0 = (const float*)d_in[3];
  const float* g0 = (const float*)d_in[4];
  const float* be0 = (const float*)d_in[5];
  const float* m0 = (const float*)d_in[6];
  const float* v0 = (const float*)d_in[7];
  const float* w1 = (const float*)d_in[8];
  const float* b1 = (const float*)d_in[9];
  const float* g1 = (const float*)d_in[10];
  const float* be1 = (const float*)d_in[11];
  const float* m1 = (const float*)d_in[12];
  const float* v1 = (const float*)d_in[13];
  const float* w2 = (const float*)d_in[14];
  const float* b2 = (const float*)d_in[15];
  const float* g2 = (const float*)d_in[16];
  const float* be2 = (const float*)d_in[17];
  const float* m2 = (const float*)d_in[18];
  const float* v2 = (const float*)d_in[19];
  const float* a = (const float*)d_in[20];

  float* out0 = (float*)d_out;                  // [B,3,S]
  float* out1 = out0 + (size_t)NB * 3 * NS;     // [B,128,S]

  int* fps = (int*)d_ws;                                        // 32 KB
  float* nxyz = (float*)((char*)d_ws + 32768);                  // 96 KB
  float* ceA = (float*)((char*)d_ws + 131072);                  // 4 MB
  float4* gq = (float4*)((char*)d_ws + 131072 + 4194304);       // 4 MB

  hipFuncSetAttribute(reinterpret_cast<const void*>(mega_kernel),
                      hipFuncAttributeMaxDynamicSharedMemorySize, SMEM_BYTES);

  fps_kernel<<<NB, 512, 0, stream>>>(xyz, fps, nxyz, out0);
  ballq_kernel<<<NB * NS, 256, 0, stream>>>(xyz, nxyz, gq);
  center_kernel<<<NB * NS, 64, 0, stream>>>(points, nxyz, fps,
      w0, b0, g0, be0, m0, v0, w1, b1, g1, be1, m1, v1,
      w2, b2, g2, be2, m2, v2, a, ceA);
  mega_kernel<<<NB * NS / QPB, MEGA_THREADS, SMEM_BYTES, stream>>>(
      points, ceA, gq,
      w0, b0, g0, be0, m0, v0, w1, b1, g1, be1, m1, v1,
      w2, b2, g2, be2, m2, v2, a, out1);
}